// Round 1
// 553.933 us; speedup vs baseline: 1.2463x; 1.2463x over previous
//
#include <hip/hip_runtime.h>
#include <hip/hip_bf16.h>

// Sizes (fixed by the problem)
#define NH   128        // hidden channels H
#define NR   6          // radial
#define NCOL 390        // 3H + 2*SH
#define TILE_E 128      // edges per tile (one block-iteration)
#define LDK  136        // padded LDS row stride (bf16 elems): 128 + 8
#define NBLK 512        // persistent blocks: 2 per CU

typedef __attribute__((ext_vector_type(8))) short bf16x8;   // 8 bf16 in 4 VGPRs
typedef __attribute__((ext_vector_type(4))) float f32x4;

__device__ __forceinline__ float fast_silu(float v) {
    // v * rcp(1 + exp(-v)) : ~5 VALU ops vs ~14 for exact-division silu.
    // rcp is 1ulp — far below the bf16-matmul error floor of this kernel.
    return v * __builtin_amdgcn_rcpf(1.0f + __expf(-v));
}

// ---------------------------------------------------------------------------
// Prep 1: combined node tables (unchanged).
//  Ci[a*3+sc][n] = emb_w[a]·lin_w[n,0:128]   + S[sc]·lin_w[n,128:131] + lin_b[n]
//  Cj[a*3+sc][n] = emb_w[a]·lin_w[n,131:259] + S[sc]·lin_w[n,259:262]
// ---------------------------------------------------------------------------
__global__ void prep_tables(const float* __restrict__ emb_w,
                            const float* __restrict__ spin_w,
                            const float* __restrict__ spin_b,
                            const float* __restrict__ lin_w,
                            const float* __restrict__ lin_b,
                            float* __restrict__ Ci, float* __restrict__ Cj) {
    int row = blockIdx.x;            // 0..569
    int n   = threadIdx.x;           // 0..127
    bool isJ = row >= 285;
    int rr = isJ ? row - 285 : row;
    int a  = rr / 3;
    int sc = rr % 3;
    const int col0 = isJ ? 131 : 0;
    const int cols = isJ ? 259 : 128;
    const float* wrow = lin_w + (size_t)n * NCOL;
    float acc = isJ ? 0.0f : lin_b[n];
    #pragma unroll 8
    for (int k = 0; k < NH; ++k)
        acc += emb_w[a * NH + k] * wrow[col0 + k];
    #pragma unroll
    for (int c = 0; c < 3; ++c)
        acc += (spin_w[c * 3 + sc] + spin_b[c]) * wrow[cols + c];
    (isJ ? Cj : Ci)[rr * NH + n] = acc;
}

// ---------------------------------------------------------------------------
// Prep 2: bf16 copy of lin_w[:, 262:390], row-major [n][k] (unchanged).
// ---------------------------------------------------------------------------
__global__ void prep_w(const float* __restrict__ lin_w, __hip_bfloat16* __restrict__ Wb) {
    int idx = blockIdx.x * 256 + threadIdx.x;       // 0..16383
    int n = idx >> 7, k = idx & 127;
    Wb[idx] = __float2bfloat16(lin_w[(size_t)n * NCOL + 262 + k]);
}

// ---------------------------------------------------------------------------
// Main fused kernel: persistent blocks, 128 edges/tile, 512 threads (8 waves).
//   - W staged into LDS ONCE per block, reused across all tiles.
//   - Next tile's rbf/indices prefetched into registers before the epilogue
//     (latency hides under MFMA + gathers + stores), committed to LDS after
//     the loop-top barrier.
//   - 3 barriers per tile.
// LDS: 34816(W) + 34816(r) + 3072(rbf) + 1024(idx) = 73728 B -> 2 blocks/CU,
// 16 waves/CU. launch_bounds(512,4) caps VGPR at 128 so 4 waves/SIMD fit.
// ---------------------------------------------------------------------------
__global__ __launch_bounds__(512, 4) void fused_main(
        const int*   __restrict__ x,   const int* __restrict__ s,
        const float* __restrict__ rbf,
        const int*   __restrict__ gi,  const int* __restrict__ gj,
        const float* __restrict__ rbf_w, const float* __restrict__ rbf_b,
        const float* __restrict__ Ci,  const float* __restrict__ Cj,
        const __hip_bfloat16* __restrict__ Wb,
        float* __restrict__ out, int E, int ntiles) {
    __shared__ __align__(16) __hip_bfloat16 w_lds[NH * LDK];
    __shared__ __align__(16) __hip_bfloat16 r_lds[TILE_E * LDK];
    __shared__ float rbf_lds[TILE_E * NR];
    __shared__ int ci_lds[TILE_E], cj_lds[TILE_E];

    const int tid = threadIdx.x;

    // ---- register-staged tile (prefetch target) ----
    float2 srbf = make_float2(0.f, 0.f);
    int sci = 0, scj = 0;

    auto load_tile = [&](int tt) {
        const int en0 = tt * TILE_E;
        if (tid < 384) {                       // 128*6 floats = 384 float2
            int nval = (E - en0 >= TILE_E ? TILE_E : E - en0) * NR;
            float2 v = make_float2(0.f, 0.f);
            if (tid * 2 < nval)
                v = ((const float2*)(rbf + (size_t)en0 * NR))[tid];
            srbf = v;
        }
        if (tid >= 384) {                      // 128 threads: i-side class
            int e = en0 + (tid - 384); if (e >= E) e = E - 1;
            int ii = gi[e];
            sci = x[ii] * 3 + s[ii];
        }
        if (tid < 128) {                       // 128 threads: j-side class
            int e = en0 + tid; if (e >= E) e = E - 1;
            int jj = gj[e];
            scj = x[jj] * 3 + s[jj];
        }
    };

    // ---- preload first tile (overlaps W staging below) ----
    const int t0 = blockIdx.x;
    const int gstride = gridDim.x;
    load_tile(t0);

    // ---- stage W once: 2048 x 16B chunks by 512 threads ----
    {
        const uint4* src = (const uint4*)Wb;            // 8 bf16 per chunk
        #pragma unroll
        for (int it = 0; it < 4; ++it) {
            int l = it * 512 + tid;                     // 0..2047
            uint4 v = src[l];
            *(uint4*)&w_lds[(l >> 4) * LDK + (l & 15) * 8] = v;
        }
    }

    // ---- loop-invariant rbf weights: k fixed per thread ----
    const int kk = tid & 127;
    const int hi = tid >> 7;                  // 0..3
    const float w0 = rbf_w[kk * NR + 0], w1 = rbf_w[kk * NR + 1], w2 = rbf_w[kk * NR + 2];
    const float w3 = rbf_w[kk * NR + 3], w4 = rbf_w[kk * NR + 4], w5 = rbf_w[kk * NR + 5];
    const float bb = rbf_b[kk];

    // ---- wave decomposition for MFMA phase ----
    const int wave   = tid >> 6;              // 0..7, each owns 16 edges
    const int lane   = tid & 63;
    const int lane15 = lane & 15;
    const int quad   = lane >> 4;
    const int e_sub  = wave * 16;
    const int e_row  = e_sub + quad * 4;      // D row base; +reg

    for (int t = t0; t < ntiles; t += gstride) {
        __syncthreads();      // (a) prev tile's LDS consumers done
        // ---- commit staged registers to LDS ----
        if (tid < 384) ((float2*)rbf_lds)[tid] = srbf;
        if (tid >= 384) ci_lds[tid - 384] = sci;
        if (tid < 128)  cj_lds[tid] = scj;
        __syncthreads();      // (b) staging visible

        // ---- r = silu(rbf @ rbf_w^T + rbf_b), bf16 into LDS ----
        #pragma unroll 4
        for (int it = 0; it < 32; ++it) {
            int e = it * 4 + hi;
            const float* re = &rbf_lds[e * NR];
            float a = bb + re[0] * w0 + re[1] * w1 + re[2] * w2
                         + re[3] * w3 + re[4] * w4 + re[5] * w5;
            r_lds[e * LDK + kk] = __float2bfloat16(fast_silu(a));
        }
        __syncthreads();      // (c) r_lds ready

        // ---- A fragments + hoisted row base pointers ----
        bf16x8 afrag[4];
        #pragma unroll
        for (int kt = 0; kt < 4; ++kt)
            afrag[kt] = *(const bf16x8*)&r_lds[(e_sub + lane15) * LDK + kt * 32 + quad * 8];

        const int e0 = t * TILE_E;
        const float* cip[4]; const float* cjp[4]; float* op[4];
        #pragma unroll
        for (int reg = 0; reg < 4; ++reg) {
            cip[reg] = Ci + ci_lds[e_row + reg] * NH + lane15;
            cjp[reg] = Cj + cj_lds[e_row + reg] * NH + lane15;
            op[reg]  = out + (size_t)(e0 + e_row + reg) * NH + lane15;
        }
        const bool tail = (e0 + TILE_E > E);

        // ---- prefetch next tile into registers (hides under epilogue) ----
        int tn = t + gstride;
        if (tn < ntiles) load_tile(tn);

        // ---- MFMA + epilogue: gathers/stores use immediate offsets only ----
        #pragma unroll
        for (int nt = 0; nt < 8; ++nt) {
            f32x4 acc = {0.f, 0.f, 0.f, 0.f};
            #pragma unroll
            for (int kt = 0; kt < 4; ++kt) {
                bf16x8 bfrag = *(const bf16x8*)&w_lds[(nt * 16 + lane15) * LDK + kt * 32 + quad * 8];
                acc = __builtin_amdgcn_mfma_f32_16x16x32_bf16(afrag[kt], bfrag, acc, 0, 0, 0);
            }
            #pragma unroll
            for (int reg = 0; reg < 4; ++reg) {
                float base = cip[reg][nt * 16] + cjp[reg][nt * 16];
                float v = acc[reg] + base;
                float sv = fast_silu(v);
                if (!tail || (e0 + e_row + reg < E))
                    __builtin_nontemporal_store(sv, op[reg] + nt * 16);
            }
        }
    }
}

// ---------------------------------------------------------------------------
extern "C" void kernel_launch(void* const* d_in, const int* in_sizes, int n_in,
                              void* d_out, int out_size, void* d_ws, size_t ws_size,
                              hipStream_t stream) {
    const int*   x      = (const int*)  d_in[0];
    const int*   s      = (const int*)  d_in[1];
    const float* rbf    = (const float*)d_in[2];
    const int*   gi     = (const int*)  d_in[3];
    const int*   gj     = (const int*)  d_in[4];
    const float* emb_w  = (const float*)d_in[5];
    const float* spin_w = (const float*)d_in[6];
    const float* spin_b = (const float*)d_in[7];
    const float* rbf_w  = (const float*)d_in[8];
    const float* rbf_b  = (const float*)d_in[9];
    const float* lin_w  = (const float*)d_in[10];
    const float* lin_b  = (const float*)d_in[11];
    const int E = in_sizes[3];

    float* Ci = (float*)d_ws;                         // 285*128 f32
    float* Cj = Ci + 285 * NH;                        // 285*128 f32
    __hip_bfloat16* Wb = (__hip_bfloat16*)(Cj + 285 * NH);  // 128*128 bf16

    prep_tables<<<570, 128, 0, stream>>>(emb_w, spin_w, spin_b, lin_w, lin_b, Ci, Cj);
    prep_w<<<64, 256, 0, stream>>>(lin_w, Wb);

    int ntiles = (E + TILE_E - 1) / TILE_E;
    int nblk = ntiles < NBLK ? ntiles : NBLK;
    fused_main<<<nblk, 512, 0, stream>>>(x, s, rbf, gi, gj, rbf_w, rbf_b,
                                         Ci, Cj, Wb, (float*)d_out, E, ntiles);
}